// Round 8
// baseline (217.681 us; speedup 1.0000x reference)
//
#include <hip/hip_runtime.h>

#define VOCAB 1024
#define HIDDEN 64
#define N_POS 131072            // 32*64*64 positions
#define Q_ELEMS 8388608

// d_out layout (floats): [0]=loss, [1..8388608]=quantized_st (NCHW),
// [8388609]=perplexity, [8388610..]=one_hot [131072,1024]
#define OUT_Q_OFF 1
#define OUT_PPL_OFF 8388609
#define OUT_OH_OFF 8388610ULL

typedef __attribute__((ext_vector_type(8))) short short8v;  // bf16x8 MFMA frag
typedef __attribute__((ext_vector_type(4))) float f32x4;

__device__ __forceinline__ short bf16r(float f) {
    union { float f; unsigned u; } v; v.f = f;
    unsigned r = v.u + 0x7FFFu + ((v.u >> 16) & 1u);   // RNE
    return (short)(r >> 16);
}

// Pre-convert codebook to bf16 rows (cbb[1024][64]) + bsq = -0.5*|c|^2.
__global__ void vq_prep(const float* __restrict__ cb, float* __restrict__ bsq,
                        unsigned short* __restrict__ cbb)
{
    const int j = blockIdx.x * 256 + threadIdx.x;     // 4 blocks -> 1024 rows
    const float4* r = (const float4*)(cb + (size_t)j * HIDDEN);
    unsigned pk[32];
    float s = 0.f;
#pragma unroll
    for (int c = 0; c < 16; ++c) {
        float4 v = r[c];
        s += v.x * v.x + v.y * v.y + v.z * v.z + v.w * v.w;
        pk[2 * c]     = (unsigned)(unsigned short)bf16r(v.x)
                      | ((unsigned)(unsigned short)bf16r(v.y) << 16);
        pk[2 * c + 1] = (unsigned)(unsigned short)bf16r(v.z)
                      | ((unsigned)(unsigned short)bf16r(v.w) << 16);
    }
    bsq[j] = -0.5f * s;
    uint4* dst = (uint4*)(cbb + (size_t)j * HIDDEN);
#pragma unroll
    for (int k = 0; k < 8; ++k)
        dst[k] = make_uint4(pk[4 * k], pk[4 * k + 1], pk[4 * k + 2], pk[4 * k + 3]);
}

// 2048 blocks x 64 threads (ONE wave per block, 8 WGs/CU, no barriers, no LDS).
// Wave owns 64 positions (cols). A-frags = bf16 codebook rows direct from
// global (L2-resident 128 KB); B-frags = x in registers; C init = -0.5*|c|^2.
// Argmax via idx-in-mantissa; loss from the max (no x reload).
__global__ __launch_bounds__(64) void vq_idx(
    const float* __restrict__ in, const float* __restrict__ cb,
    const unsigned short* __restrict__ cbb, const float* __restrict__ bsq,
    float* __restrict__ out, float* __restrict__ ws_loss,
    unsigned* __restrict__ counts)
{
    const int lane = threadIdx.x;
    const int l15  = lane & 15;
    const int kg   = lane >> 4;       // k-group 0..3
    const int kg4  = kg << 2;

    const int base = blockIdx.x * 64;
    const int b    = base >> 12;      // NCHW batch index, uniform
    const int hw0  = base & 4095;

    // ---- x fragments + per-lane |x|^2 partials ----
    // B-frag: col = l15 within tile bt, k = kh*32 + kg*8 + e
    short8v xf[4][2];
    float rm[4], xsq[4];
#pragma unroll
    for (int bt = 0; bt < 4; ++bt) {
        xsq[bt] = 0.f;
        rm[bt]  = -3.4e38f;
#pragma unroll
        for (int kh = 0; kh < 2; ++kh) {
            const float* xp = in + (size_t)b * 262144
                            + (size_t)(kh * 32 + kg * 8) * 4096
                            + hw0 + bt * 16 + l15;
            short8v v;
#pragma unroll
            for (int e = 0; e < 8; ++e) {
                float x = xp[(size_t)e * 4096];
                xsq[bt] = fmaf(x, x, xsq[bt]);
                v[e] = bf16r(x);
            }
            xf[bt][kh] = v;
        }
    }

    // ---- scan all 1024 codes: A-frags straight from global (L2-hot) ----
#pragma unroll 2
    for (int ct = 0; ct < 64; ++ct) {
        const unsigned short* arow = cbb + (size_t)(ct * 16 + l15) * HIDDEN;
        short8v a0 = *(const short8v*)(arow + kg * 8);        // k 0..31
        short8v a1 = *(const short8v*)(arow + 32 + kg * 8);   // k 32..63
        f32x4 bsq4 = *(const f32x4*)&bsq[ct * 16 + kg4];
        const unsigned jb = (unsigned)(ct * 16 + kg4);
#pragma unroll
        for (int bt = 0; bt < 4; ++bt) {
            f32x4 acc = bsq4;
            acc = __builtin_amdgcn_mfma_f32_16x16x32_bf16(a0, xf[bt][0], acc, 0, 0, 0);
            acc = __builtin_amdgcn_mfma_f32_16x16x32_bf16(a1, xf[bt][1], acc, 0, 0, 0);
#pragma unroll
            for (int r = 0; r < 4; ++r) {
                unsigned pj = (__float_as_uint(acc[r]) & 0xFFFFFC00u) | (jb + r);
                rm[bt] = fmaxf(rm[bt], __uint_as_float(pj));
            }
        }
    }

    // ---- full butterfly over kg: every lane gets max + |x|^2 for its cols ----
    float mred[4], xred[4];
#pragma unroll
    for (int bt = 0; bt < 4; ++bt) {
        float m = rm[bt], xs = xsq[bt];
        m  = fmaxf(m, __shfl_xor(m, 16));
        xs += __shfl_xor(xs, 16);
        m  = fmaxf(m, __shfl_xor(m, 32));
        xs += __shfl_xor(xs, 32);
        mred[bt] = m; xred[bt] = xs;
    }
    // lane L owns col L: bt = L>>4 (static selects -- no dynamic reg indexing)
    const int sel = lane >> 4;
    const float m  = sel == 0 ? mred[0] : sel == 1 ? mred[1]
                   : sel == 2 ? mred[2] : mred[3];
    const float xs = sel == 0 ? xred[0] : sel == 1 ? xred[1]
                   : sel == 2 ? xred[2] : xred[3];
    const unsigned mu = __float_as_uint(m);
    const int   jf   = (int)(mu & 1023u);
    const float mval = __uint_as_float(mu & 0xFFFFFC00u);
    float lsum = xs - 2.f * mval;    // |x-c|^2 = |x|^2 - 2*(x.c - 0.5|c|^2)

    // ---- histogram (one atomic per lane) ----
    atomicAdd(&counts[jf], 1u);

    // ---- q write: gather fp32 code row, store NCHW (quantized_st == q) ----
    {
        const float4* cr4 = (const float4*)(cb + (size_t)jf * HIDDEN);
        float* qp = out + OUT_Q_OFF + (size_t)b * 262144 + hw0 + lane;
#pragma unroll
        for (int c4 = 0; c4 < 16; ++c4) {
            float4 v = cr4[c4];
            __builtin_nontemporal_store(v.x, &qp[(size_t)(4 * c4 + 0) * 4096]);
            __builtin_nontemporal_store(v.y, &qp[(size_t)(4 * c4 + 1) * 4096]);
            __builtin_nontemporal_store(v.z, &qp[(size_t)(4 * c4 + 2) * 4096]);
            __builtin_nontemporal_store(v.w, &qp[(size_t)(4 * c4 + 3) * 4096]);
        }
    }

    // ---- the single 1.0 per row (zeros laid down by hipMemsetAsync) ----
    out[OUT_OH_OFF + (size_t)(base + lane) * VOCAB + jf] = 1.0f;

    // ---- wave-reduce loss -> low-contention atomic tree ----
#pragma unroll
    for (int off = 32; off; off >>= 1) lsum += __shfl_down(lsum, off);
    if (lane == 0) atomicAdd(&ws_loss[blockIdx.x & 63], lsum);
}

__global__ void vq_finalize(const unsigned* __restrict__ counts,
                            const float* __restrict__ ws_loss,
                            float* __restrict__ out)
{
    __shared__ double red[4];
    const int tid = threadIdx.x;
    double s = 0.0;
    for (int k = tid; k < VOCAB; k += 256) {
        double p = (double)counts[k] / (double)N_POS;
        s += -p * log(p + 1e-10);
    }
#pragma unroll
    for (int off = 32; off; off >>= 1) s += __shfl_down(s, off);
    if ((tid & 63) == 0) red[tid >> 6] = s;
    __syncthreads();
    if (tid == 0) {
        double e = red[0] + red[1] + red[2] + red[3];
        out[OUT_PPL_OFF] = (float)exp(e);
        float l = 0.f;
#pragma unroll
        for (int k = 0; k < 64; ++k) l += ws_loss[k];
        out[0] = l * 1.25f / (float)Q_ELEMS;
    }
}

extern "C" void kernel_launch(void* const* d_in, const int* in_sizes, int n_in,
                              void* d_out, int out_size, void* d_ws, size_t ws_size,
                              hipStream_t stream) {
    const float* in = (const float*)d_in[0];
    const float* cb = (const float*)d_in[1];
    float* out = (float*)d_out;

    // ws layout: [0,256)B loss slots (64 f32) | [256,4352)B counts (1024 u32)
    //            [8192,12288)B bsq (1024 f32) | [16384,147456)B cbb bf16
    float*          ws_loss = (float*)d_ws;
    unsigned*       counts  = (unsigned*)d_ws + 64;
    float*          bsq     = (float*)d_ws + 2048;
    unsigned short* cbb     = (unsigned short*)((char*)d_ws + 16384);

    // bulk-zero one_hot at fill-kernel rate (proven 6.6 TB/s), then light kernels
    hipMemsetAsync(out + OUT_OH_OFF, 0, (size_t)N_POS * VOCAB * sizeof(float), stream);
    hipMemsetAsync(d_ws, 0, 4352, stream);           // loss slots + counts
    vq_prep<<<4, 256, 0, stream>>>(cb, bsq, cbb);
    vq_idx<<<2048, 64, 0, stream>>>(in, cb, cbb, bsq, out, ws_loss, counts);
    vq_finalize<<<1, 256, 0, stream>>>(counts, ws_loss, out);
}

// Round 9
// 160.955 us; speedup vs baseline: 1.3524x; 1.3524x over previous
//
#include <hip/hip_runtime.h>

#define VOCAB 1024
#define HIDDEN 64
#define N_POS 131072            // 32*64*64 positions
#define Q_ELEMS 8388608
#define BPOS 128                // positions per block
#define NBLK 1024               // 4 blocks per CU

// d_out layout (floats): [0]=loss, [1..8388608]=quantized_st (NCHW),
// [8388609]=perplexity, [8388610..]=one_hot [131072,1024]
#define OUT_Q_OFF 1
#define OUT_PPL_OFF 8388609
#define OUT_OH_OFF 8388610ULL

typedef __attribute__((ext_vector_type(8))) short short8v;  // bf16x8 MFMA frag
typedef __attribute__((ext_vector_type(4))) float f32x4;

__device__ __forceinline__ short bf16r(float f) {
    union { float f; unsigned u; } v; v.f = f;
    unsigned r = v.u + 0x7FFFu + ((v.u >> 16) & 1u);   // RNE
    return (short)(r >> 16);
}

// 256 threads (4 waves), 128 positions, 4 blocks/CU (16 waves/CU).
// Per 256-code chunk: stage to LDS -> issue 1/4 of the one_hot zero stream
// (drains under MFMA) -> MFMA argmax. Cross-block TLP keeps the CU's store
// pipe busy while any one block sits at its chunk barrier.
__global__ __launch_bounds__(256, 4) void vq_main(
    const float* __restrict__ in, const float* __restrict__ cb,
    float* __restrict__ out, float* __restrict__ ws_loss,
    unsigned* __restrict__ counts)
{
    __shared__ short cbs[256 * HIDDEN];     // 32 KB, one chunk, XOR-swizzled
    __shared__ float bsqs[256];             // -0.5*|c|^2 (chunk-local)
    __shared__ unsigned hist[VOCAB];        // 4 KB
    __shared__ int idx_lds[BPOS];

    const int tid  = threadIdx.x;
    const int wid  = tid >> 6;
    const int lane = tid & 63;
    const int l15  = lane & 15;
    const int kg   = lane >> 4;        // k-group 0..3
    const int kg4  = kg << 2;
    const int kgb  = kg << 4;

    const int base = blockIdx.x * BPOS;
    const int b    = base >> 12;       // NCHW batch index, uniform per block
    const int hw0  = base & 4095;

    float* ohflat = out + OUT_OH_OFF + (size_t)base * VOCAB;   // 131072 floats
    float4* oh4   = (float4*)(ohflat + 2);                     // 16B aligned
    const float4 z4 = make_float4(0.f, 0.f, 0.f, 0.f);
    if (tid == 0)   *(float2*)ohflat = make_float2(0.f, 0.f);              // head
    if (tid == 255) *(float2*)(ohflat + 131070) = make_float2(0.f, 0.f);   // tail

    for (int k = tid; k < VOCAB; k += 256) hist[k] = 0u;

    // ---- x fragments + per-lane |x|^2: wave covers positions [wid*32, +32) ----
    short8v xf[2][2];
    float xsq[2], rm[2];
#pragma unroll
    for (int bt = 0; bt < 2; ++bt) {
        xsq[bt] = 0.f;
        rm[bt]  = -3.4e38f;
#pragma unroll
        for (int kh = 0; kh < 2; ++kh) {
            const float* xp = in + (size_t)b * 262144
                            + (size_t)(kh * 32 + kg * 8) * 4096
                            + hw0 + wid * 32 + bt * 16 + l15;
            short8v v;
#pragma unroll
            for (int e = 0; e < 8; ++e) {
                float x = xp[(size_t)e * 4096];
                xsq[bt] = fmaf(x, x, xsq[bt]);
                v[e] = bf16r(x);
            }
            xf[bt][kh] = v;
        }
    }

    // ---- chunked scan: stage -> zero-stream share -> MFMA ----
    for (int ch = 0; ch < 4; ++ch) {
        __syncthreads();
        {   // stage 256 codes as bf16, XOR-swizzled: byte ^= (row&7)<<4
            const float4* src = (const float4*)(cb + (size_t)ch * 256 * HIDDEN);
#pragma unroll
            for (int it = 0; it < 16; ++it) {
                int i = tid + it * 256;
                int row = i >> 4, c4 = i & 15;
                float4 v = src[i];
                float ss = v.x * v.x + v.y * v.y + v.z * v.z + v.w * v.w;
                ss += __shfl_xor(ss, 1);
                ss += __shfl_xor(ss, 2);
                ss += __shfl_xor(ss, 4);
                ss += __shfl_xor(ss, 8);
                unsigned lo = ((unsigned)(unsigned short)bf16r(v.x))
                            | ((unsigned)(unsigned short)bf16r(v.y) << 16);
                unsigned hi = ((unsigned)(unsigned short)bf16r(v.z))
                            | ((unsigned)(unsigned short)bf16r(v.w) << 16);
                int boff = row * 128 + ((c4 * 8) ^ ((row & 7) << 4));
                *(uint2*)((char*)cbs + boff) = make_uint2(lo, hi);
                if (c4 == 0) bsqs[row] = -0.5f * ss;
            }
        }
        __syncthreads();

        // issue this chunk's quarter of the zero stream (fire-and-forget;
        // drains under the MFMA phase / other blocks' phases)
        {
            const int s1 = (ch == 3) ? 32767 : (ch + 1) * 8192;
            for (int s = ch * 8192 + tid; s < s1; s += 256) oh4[s] = z4;
        }

        for (int ct = 0; ct < 16; ++ct) {
            const int rbase = ct * 16 + l15;          // A-frag row (chunk-local)
            const char* arow = (const char*)cbs + rbase * 128;
            const int sw = (rbase & 7) << 4;
            short8v a0 = *(const short8v*)(arow + (kgb ^ sw));          // k 0..31
            short8v a1 = *(const short8v*)(arow + ((64 + kgb) ^ sw));   // k 32..63
            f32x4 bsq4 = *(const f32x4*)&bsqs[ct * 16 + kg4];
            const unsigned jb = (unsigned)(ch * 256 + ct * 16 + kg4);
#pragma unroll
            for (int bt = 0; bt < 2; ++bt) {
                f32x4 acc = bsq4;
                acc = __builtin_amdgcn_mfma_f32_16x16x32_bf16(a0, xf[bt][0], acc, 0, 0, 0);
                acc = __builtin_amdgcn_mfma_f32_16x16x32_bf16(a1, xf[bt][1], acc, 0, 0, 0);
#pragma unroll
                for (int r = 0; r < 4; ++r) {
                    unsigned pj = (__float_as_uint(acc[r]) & 0xFFFFFC00u) | (jb + r);
                    rm[bt] = fmaxf(rm[bt], __uint_as_float(pj));
                }
            }
        }
    }

    // ---- kg-reduce: max + |x|^2; idx, hist, loss from the max ----
    float lsum = 0.f;
#pragma unroll
    for (int bt = 0; bt < 2; ++bt) {
        float m  = rm[bt];
        float xs = xsq[bt];
        m  = fmaxf(m, __shfl_xor(m, 16));
        xs += __shfl_xor(xs, 16);
        m  = fmaxf(m, __shfl_xor(m, 32));
        xs += __shfl_xor(xs, 32);
        if (kg == 0) {
            unsigned mu = __float_as_uint(m);
            int j = (int)(mu & 1023u);
            float mval = __uint_as_float(mu & 0xFFFFFC00u);
            idx_lds[wid * 32 + bt * 16 + l15] = j;
            atomicAdd(&hist[j], 1u);
            lsum += xs - 2.f * mval;    // |x-c|^2 = |x|^2 - 2(x.c - 0.5|c|^2)
        }
    }
    __syncthreads();   // drains all zero-stores; idx_lds/hist visible

    // ---- the 1.0 scatter (after zeros are committed) ----
    if (tid < BPOS) {
        const int jf = idx_lds[tid];
        ohflat[(size_t)tid * VOCAB + jf] = 1.0f;
    }

    // ---- q writes: thread t -> position tid&127, channels [(tid>>7)*32, +32) ----
    {
        const int p   = tid & 127;
        const int ch0 = (tid >> 7) * 32;
        const int jf  = idx_lds[p];
        const float4* cr4 = (const float4*)(cb + (size_t)jf * HIDDEN + ch0);
        float* qp = out + OUT_Q_OFF + (size_t)b * 262144
                  + (size_t)ch0 * 4096 + hw0 + p;
#pragma unroll
        for (int c4 = 0; c4 < 8; ++c4) {
            float4 v = cr4[c4];
            __builtin_nontemporal_store(v.x, &qp[(size_t)(4 * c4 + 0) * 4096]);
            __builtin_nontemporal_store(v.y, &qp[(size_t)(4 * c4 + 1) * 4096]);
            __builtin_nontemporal_store(v.z, &qp[(size_t)(4 * c4 + 2) * 4096]);
            __builtin_nontemporal_store(v.w, &qp[(size_t)(4 * c4 + 3) * 4096]);
        }
    }

    // ---- flush histogram, reduce loss ----
    for (int k = tid; k < VOCAB; k += 256) {
        unsigned h = hist[k];
        if (h) atomicAdd(&counts[k], h);
    }
#pragma unroll
    for (int off = 32; off; off >>= 1) lsum += __shfl_down(lsum, off);
    if (lane == 0) atomicAdd(&ws_loss[blockIdx.x & 63], lsum);
}

__global__ void vq_finalize(const unsigned* __restrict__ counts,
                            const float* __restrict__ ws_loss,
                            float* __restrict__ out)
{
    __shared__ double red[4];
    const int tid = threadIdx.x;
    double s = 0.0;
    for (int k = tid; k < VOCAB; k += 256) {
        double p = (double)counts[k] / (double)N_POS;
        s += -p * log(p + 1e-10);
    }
#pragma unroll
    for (int off = 32; off; off >>= 1) s += __shfl_down(s, off);
    if ((tid & 63) == 0) red[tid >> 6] = s;
    __syncthreads();
    if (tid == 0) {
        double e = red[0] + red[1] + red[2] + red[3];
        out[OUT_PPL_OFF] = (float)exp(e);
        float l = 0.f;
#pragma unroll
        for (int k = 0; k < 64; ++k) l += ws_loss[k];
        out[0] = l * 1.25f / (float)Q_ELEMS;
    }
}

extern "C" void kernel_launch(void* const* d_in, const int* in_sizes, int n_in,
                              void* d_out, int out_size, void* d_ws, size_t ws_size,
                              hipStream_t stream) {
    const float* in = (const float*)d_in[0];
    const float* cb = (const float*)d_in[1];
    float* out = (float*)d_out;

    float*    ws_loss = (float*)d_ws;                 // 64 f32 slots
    unsigned* counts  = (unsigned*)d_ws + 64;         // 1024 u32

    hipMemsetAsync(d_ws, 0, 4352, stream);            // zero loss slots + counts
    vq_main<<<NBLK, 256, 0, stream>>>(in, cb, out, ws_loss, counts);
    vq_finalize<<<1, 256, 0, stream>>>(counts, ws_loss, out);
}